// Round 1
// baseline (149.617 us; speedup 1.0000x reference)
//
#include <hip/hip_runtime.h>

// ---------------------------------------------------------------------------
// UniversalBlockEncoder: algebraically folded attention pooling.
//
//   u_i = silu(W1 x_i + b1)                       (the only per-point nonlinearity)
//   s_h(i) = g_h . u_i + d_h    with g_h = W2^T (scale Wk_h^T q_h)
//   p = exp(s)  (no max-subtraction: scores are O(3), f32-safe)
//   T_h = sum_i p_h(i) u_i ,  l_h = sum_i p_h(i)
//   out = Wo ( Wv ( W2 (T/l) + b2 ) + bv ) + bo
// ---------------------------------------------------------------------------

#define LOG2E 1.44269504088896340736f
#define NLN2  (-0.69314718055994530942f)

#if __has_builtin(__builtin_amdgcn_exp2f)
#define EXP2(x) __builtin_amdgcn_exp2f(x)
#else
#define EXP2(x) exp2f(x)
#endif
#if __has_builtin(__builtin_amdgcn_rcpf)
#define RCP(x) __builtin_amdgcn_rcpf(x)
#else
#define RCP(x) (1.0f / (x))
#endif

// workspace float offsets
#define WS_C4   0      // 64 x float4 : {-log2e*W1[j][0], -log2e*W1[j][1], -log2e*b1[j], 0}
#define WS_G4   256    // 64 x float4 : log2e * g_h[j], h=0..3
#define WS_D    512    // 4           : log2e * d_h
#define WS_ACC  768    // NSLOT x SLOTSTRIDE accumulators: [0..3]=l_h, [4+h*64+j]=T_h[j]
#define NSLOT      16
#define SLOTSTRIDE 264

#define NPTS       (1024 * 1024)
#define NGROUPS    (NPTS / 64)          // 16384
#define K1_BLOCKS  1024
#define K1_THREADS 128
#define WAVES_TOTAL (K1_BLOCKS * (K1_THREADS / 64))   // 2048
#define GROUPS_PER_WAVE (NGROUPS / WAVES_TOTAL)       // 8

// ---------------------------------------------------------------------------
__global__ void setup_kernel(const float* __restrict__ W1, const float* __restrict__ b1,
                             const float* __restrict__ W2, const float* __restrict__ b2,
                             const float* __restrict__ query,
                             const float* __restrict__ ipw, const float* __restrict__ ipb,
                             float* __restrict__ ws)
{
    __shared__ float qs[64];
    __shared__ float as[4 * 64];
    const int t = threadIdx.x;

    // zero the atomic accumulator slots (ws is poisoned before each launch)
    for (int i = t; i < NSLOT * SLOTSTRIDE; i += 256) ws[WS_ACC + i] = 0.0f;

    // q = Wq @ query + bq   (Wq = in_proj_w rows 0..63)
    if (t < 64) {
        float acc = ipb[t];
        for (int k = 0; k < 64; ++k) acc += ipw[t * 64 + k] * query[k];
        qs[t] = acc;
    }
    __syncthreads();

    // a_h[k] = scale * sum_m Wk[h*16+m][k] * q[h*16+m]   (Wk = rows 64..127, scale=0.25)
    {
        const int h = t >> 6, k = t & 63;
        float acc = 0.0f;
        for (int m = 0; m < 16; ++m)
            acc += ipw[(64 + h * 16 + m) * 64 + k] * qs[h * 16 + m];
        as[h * 64 + k] = 0.25f * acc;
    }
    __syncthreads();

    if (t < 64) {
        const int j = t;
        for (int h = 0; h < 4; ++h) {
            float g = 0.0f;
            for (int d = 0; d < 64; ++d) g += as[h * 64 + d] * W2[d * 64 + j];
            ws[WS_G4 + j * 4 + h] = LOG2E * g;
        }
        ws[WS_C4 + j * 4 + 0] = -LOG2E * W1[2 * j];
        ws[WS_C4 + j * 4 + 1] = -LOG2E * W1[2 * j + 1];
        ws[WS_C4 + j * 4 + 2] = -LOG2E * b1[j];
        ws[WS_C4 + j * 4 + 3] = 0.0f;
    }
    if (t < 4) {
        float d = 0.0f;
        for (int c = 0; c < 64; ++c) d += as[t * 64 + c] * b2[c];
        float qb = 0.0f;
        for (int m = 0; m < 16; ++m) qb += qs[t * 16 + m] * ipb[64 + t * 16 + m];
        ws[WS_D + t] = LOG2E * (d + 0.25f * qb);
    }
}

// ---------------------------------------------------------------------------
// Main kernel: 2 waves/block, each wave independently processes 64-point groups.
// Phase 1 (lane = point): u_j via silu, score dot-products, stage u -> LDS.
// Phase 2 (lane = j):     T_h[j] += p_h(pt) * u[pt][j]  (outer-product accum).
__global__ __launch_bounds__(K1_THREADS) void main_kernel(
        const float* __restrict__ rr, const float* __restrict__ ri,
        float* __restrict__ ws)
{
    __shared__ float4 c4s[64];
    __shared__ float4 g4s[64];
    __shared__ float  us[2][64 * 65];   // [j][pt], +1 pad -> 2-way bank aliasing (free)
    __shared__ float4 p4s[2][64];

    const int t    = threadIdx.x;
    const int lane = t & 63;
    const int w    = t >> 6;

    if (t < 64) c4s[t]       = ((const float4*)(ws + WS_C4))[t];
    else        g4s[t - 64]  = ((const float4*)(ws + WS_G4))[t - 64];
    const float d0 = ws[WS_D + 0], d1 = ws[WS_D + 1];
    const float d2 = ws[WS_D + 2], d3 = ws[WS_D + 3];
    __syncthreads();

    const int gwave = blockIdx.x * 2 + w;
    float l0 = 0, l1 = 0, l2 = 0, l3 = 0;
    float t0 = 0, t1 = 0, t2 = 0, t3 = 0;
    float* uw = us[w];

    for (int it = 0; it < GROUPS_PER_WAVE; ++it) {
        const int g   = gwave + it * WAVES_TOTAL;
        const int idx = g * 64 + lane;          // exact: 16384*64 == NPTS
        const float r  = rr[idx];
        const float im = ri[idx];

        float s0 = d0, s1 = d1, s2 = d2, s3 = d3;
        #pragma unroll 16
        for (int j = 0; j < 64; ++j) {
            const float4 c  = c4s[j];           // broadcast ds_read_b128
            const float4 gg = g4s[j];
            const float zn = fmaf(c.x, r, fmaf(c.y, im, c.z));   // -log2e * z
            const float e  = EXP2(zn);                           // exp(-z)
            const float rc = RCP(1.0f + e);                      // sigmoid(z)
            const float u  = zn * NLN2 * rc;                     // z * sigmoid(z)
            s0 = fmaf(gg.x, u, s0);
            s1 = fmaf(gg.y, u, s1);
            s2 = fmaf(gg.z, u, s2);
            s3 = fmaf(gg.w, u, s3);
            uw[j * 65 + lane] = u;
        }
        // p_h = exp2(s'_h)  (log2e folded into g and d)
        const float p0 = EXP2(s0), p1 = EXP2(s1), p2 = EXP2(s2), p3 = EXP2(s3);
        l0 += p0; l1 += p1; l2 += p2; l3 += p3;
        p4s[w][lane] = make_float4(p0, p1, p2, p3);
        __syncthreads();

        #pragma unroll 16
        for (int p = 0; p < 64; ++p) {
            const float  uu = uw[lane * 65 + p];   // 2-way aliasing, free
            const float4 pv = p4s[w][p];           // broadcast
            t0 = fmaf(pv.x, uu, t0);
            t1 = fmaf(pv.y, uu, t1);
            t2 = fmaf(pv.z, uu, t2);
            t3 = fmaf(pv.w, uu, t3);
        }
        __syncthreads();   // before next iteration overwrites uw/p4s
    }

    // wave-reduce l (lane-local partials)
    for (int m = 1; m < 64; m <<= 1) {
        l0 += __shfl_xor(l0, m);
        l1 += __shfl_xor(l1, m);
        l2 += __shfl_xor(l2, m);
        l3 += __shfl_xor(l3, m);
    }

    float* acc = ws + WS_ACC + (blockIdx.x & (NSLOT - 1)) * SLOTSTRIDE;
    if (lane == 0) {
        atomicAdd(acc + 0, l0);
        atomicAdd(acc + 1, l1);
        atomicAdd(acc + 2, l2);
        atomicAdd(acc + 3, l3);
    }
    atomicAdd(acc + 4 + 0 * 64 + lane, t0);
    atomicAdd(acc + 4 + 1 * 64 + lane, t1);
    atomicAdd(acc + 4 + 2 * 64 + lane, t2);
    atomicAdd(acc + 4 + 3 * 64 + lane, t3);
}

// ---------------------------------------------------------------------------
__global__ void finish_kernel(const float* __restrict__ W2, const float* __restrict__ b2,
                              const float* __restrict__ ipw, const float* __restrict__ ipb,
                              const float* __restrict__ opw, const float* __restrict__ opb,
                              const float* __restrict__ ws, float* __restrict__ out)
{
    __shared__ float red[260];   // [0..3]=l, [4+h*64+k]=T
    __shared__ float sb[256];    // S-bar per (h, j)
    __shared__ float pl[64];     // pooled
    const int t = threadIdx.x;

    {
        float a = 0.0f;
        for (int s = 0; s < NSLOT; ++s) a += ws[WS_ACC + s * SLOTSTRIDE + t];
        red[t] = a;
        if (t < 4) {
            float a2 = 0.0f;
            for (int s = 0; s < NSLOT; ++s) a2 += ws[WS_ACC + s * SLOTSTRIDE + 256 + t];
            red[256 + t] = a2;
        }
    }
    __syncthreads();

    // S-bar_h[j] = W2[j][:] . (T_h / l_h) + b2[j]
    {
        const int h = t >> 6, j = t & 63;
        const float inv = 1.0f / red[h];
        float a = 0.0f;
        for (int k = 0; k < 64; ++k) a += W2[j * 64 + k] * red[4 + h * 64 + k];
        sb[t] = fmaf(inv, a, b2[j]);
    }
    __syncthreads();

    // pooled[t] = Wv[t][:] . S-bar_h + bv[t]   (Wv = in_proj_w rows 128..191)
    if (t < 64) {
        const int h = t >> 4;
        float a = ipb[128 + t];
        for (int d = 0; d < 64; ++d) a += ipw[(128 + t) * 64 + d] * sb[h * 64 + d];
        pl[t] = a;
    }
    __syncthreads();

    if (t < 64) {
        float a = opb[t];
        for (int p = 0; p < 64; ++p) a += opw[t * 64 + p] * pl[p];
        out[t] = a;
    }
}

// ---------------------------------------------------------------------------
extern "C" void kernel_launch(void* const* d_in, const int* in_sizes, int n_in,
                              void* d_out, int out_size, void* d_ws, size_t ws_size,
                              hipStream_t stream)
{
    const float* rr  = (const float*)d_in[0];   // rho_real  (1024*1024)
    const float* ri  = (const float*)d_in[1];   // rho_imag  (1024*1024)
    // d_in[2..5]: l_A, l_B, Z_A, Z_B — unused by the reference
    const float* W1  = (const float*)d_in[6];   // (64,2)
    const float* b1  = (const float*)d_in[7];   // (64,)
    const float* W2  = (const float*)d_in[8];   // (64,64)
    const float* b2  = (const float*)d_in[9];   // (64,)
    const float* qy  = (const float*)d_in[10];  // (1,64)
    const float* ipw = (const float*)d_in[11];  // (192,64)
    const float* ipb = (const float*)d_in[12];  // (192,)
    const float* opw = (const float*)d_in[13];  // (64,64)
    const float* opb = (const float*)d_in[14];  // (64,)
    float* ws  = (float*)d_ws;
    float* out = (float*)d_out;

    setup_kernel<<<1, 256, 0, stream>>>(W1, b1, W2, b2, qy, ipw, ipb, ws);
    main_kernel<<<K1_BLOCKS, K1_THREADS, 0, stream>>>(rr, ri, ws);
    finish_kernel<<<1, 256, 0, stream>>>(W2, b2, ipw, ipb, opw, opb, ws, out);
}

// Round 2
// 139.156 us; speedup vs baseline: 1.0752x; 1.0752x over previous
//
#include <hip/hip_runtime.h>

// ---------------------------------------------------------------------------
// UniversalBlockEncoder: algebraically folded attention pooling.
//
//   u_i = silu(W1 x_i + b1)                 (the only per-point nonlinearity)
//   s_h(i) = g_h . u_i + d_h    with g_h = W2^T (scale Wk_h^T q_h)
//   p = exp(s)  (no max-subtraction: scores are O(3), f32-safe)
//   T_h = sum_i p_h(i) u_i ,  l_h = sum_i p_h(i)
//   out = Wo ( Wv ( W2 (T/l) + b2 ) + bv ) + bo
//
// R2: bf16 u-staging + constants out of LDS -> 18.9 KB LDS -> 8 blocks/CU.
// ---------------------------------------------------------------------------

#define LOG2E 1.44269504088896340736f
#define NLN2  (-0.69314718055994530942f)

#if __has_builtin(__builtin_amdgcn_exp2f)
#define EXP2(x) __builtin_amdgcn_exp2f(x)
#else
#define EXP2(x) exp2f(x)
#endif
#if __has_builtin(__builtin_amdgcn_rcpf)
#define RCP(x) __builtin_amdgcn_rcpf(x)
#else
#define RCP(x) (1.0f / (x))
#endif

// workspace float offsets
#define WS_C4   0      // 64 x float4 : {-log2e*W1[j][0], -log2e*W1[j][1], -log2e*b1[j], 0}
#define WS_G4   256    // 64 x float4 : log2e * g_h[j], h=0..3
#define WS_D    512    // 4           : log2e * d_h
#define WS_ACC  768    // NSLOT x SLOTSTRIDE accumulators: [0..3]=l_h, [4+h*64+j]=T_h[j]
#define NSLOT      32
#define SLOTSTRIDE 272   // 64B-aligned slot stride

#define NPTS       (1024 * 1024)
#define NGROUPS    (NPTS / 64)          // 16384
#define K1_BLOCKS  2048
#define K1_THREADS 128
#define WAVES_TOTAL (K1_BLOCKS * (K1_THREADS / 64))   // 4096
#define GROUPS_PER_WAVE (NGROUPS / WAVES_TOTAL)       // 4

#define WG_FENCE() __builtin_amdgcn_fence(__ATOMIC_ACQ_REL, "workgroup")

// ---------------------------------------------------------------------------
__global__ void setup_kernel(const float* __restrict__ W1, const float* __restrict__ b1,
                             const float* __restrict__ W2, const float* __restrict__ b2,
                             const float* __restrict__ query,
                             const float* __restrict__ ipw, const float* __restrict__ ipb,
                             float* __restrict__ ws)
{
    __shared__ float qs[64];
    __shared__ float as[4 * 64];
    const int t = threadIdx.x;

    // q = Wq @ query + bq   (Wq = in_proj_w rows 0..63)
    if (t < 64) {
        float acc = ipb[t];
        for (int k = 0; k < 64; ++k) acc += ipw[t * 64 + k] * query[k];
        qs[t] = acc;
    }
    __syncthreads();

    // a_h[k] = scale * sum_m Wk[h*16+m][k] * q[h*16+m]   (Wk = rows 64..127, scale=0.25)
    {
        const int h = t >> 6, k = t & 63;
        float acc = 0.0f;
        for (int m = 0; m < 16; ++m)
            acc += ipw[(64 + h * 16 + m) * 64 + k] * qs[h * 16 + m];
        as[h * 64 + k] = 0.25f * acc;
    }
    __syncthreads();

    if (t < 64) {
        const int j = t;
        for (int h = 0; h < 4; ++h) {
            float g = 0.0f;
            for (int d = 0; d < 64; ++d) g += as[h * 64 + d] * W2[d * 64 + j];
            ws[WS_G4 + j * 4 + h] = LOG2E * g;
        }
        ws[WS_C4 + j * 4 + 0] = -LOG2E * W1[2 * j];
        ws[WS_C4 + j * 4 + 1] = -LOG2E * W1[2 * j + 1];
        ws[WS_C4 + j * 4 + 2] = -LOG2E * b1[j];
        ws[WS_C4 + j * 4 + 3] = 0.0f;
    }
    if (t < 4) {
        float d = 0.0f;
        for (int c = 0; c < 64; ++c) d += as[t * 64 + c] * b2[c];
        float qb = 0.0f;
        for (int m = 0; m < 16; ++m) qb += qs[t * 16 + m] * ipb[64 + t * 16 + m];
        ws[WS_D + t] = LOG2E * (d + 0.25f * qb);
    }
}

// ---------------------------------------------------------------------------
// Main kernel: 2 independent waves/block, each processes 64-point groups.
// Phase 1 (lane = point): u_j via silu, score dot-products, stage bf16 u -> LDS.
// Phase 2 (lane = j):     T_h[j] += p_h(pt) * u[pt][j]  (outer-product accum).
// Waves never read each other's LDS half -> workgroup fence (lgkmcnt wait)
// instead of s_barrier; waves stay decoupled.
__global__ __launch_bounds__(K1_THREADS) void main_kernel(
        const float* __restrict__ rr, const float* __restrict__ ri,
        const float4* __restrict__ c4g, const float4* __restrict__ g4g,
        const float* __restrict__ dvec, float* __restrict__ accb)
{
    __shared__ unsigned short us[2][64 * 66];  // [j][pt] bf16, stride 66 -> 2-way banks (free)
    __shared__ float4 p4s[2][64];

    const int t    = threadIdx.x;
    const int lane = t & 63;
    const int w    = t >> 6;

    const float d0 = dvec[0], d1 = dvec[1], d2 = dvec[2], d3 = dvec[3];

    const int gwave = blockIdx.x * 2 + w;
    float l0 = 0, l1 = 0, l2 = 0, l3 = 0;
    float t0 = 0, t1 = 0, t2 = 0, t3 = 0;
    unsigned short* uw = us[w];

    for (int it = 0; it < GROUPS_PER_WAVE; ++it) {
        const int g   = gwave + it * WAVES_TOTAL;
        const int idx = g * 64 + lane;          // exact: 16384*64 == NPTS
        const float r  = rr[idx];
        const float im = ri[idx];

        float s0 = d0, s1 = d1, s2 = d2, s3 = d3;
        #pragma unroll 16
        for (int j = 0; j < 64; ++j) {
            const float4 c  = c4g[j];            // wave-uniform -> scalar/broadcast load
            const float4 gg = g4g[j];
            const float zn = fmaf(c.x, r, fmaf(c.y, im, c.z));   // -log2e * z
            const float e  = EXP2(zn);                           // exp(-z)
            const float rc = RCP(1.0f + e);                      // sigmoid(z)
            const float u  = zn * NLN2 * rc;                     // z * sigmoid(z)
            s0 = fmaf(gg.x, u, s0);
            s1 = fmaf(gg.y, u, s1);
            s2 = fmaf(gg.z, u, s2);
            s3 = fmaf(gg.w, u, s3);
            // bf16 round-half-up (unbiased to ~2^-17 rel; errors average over 1M pts)
            uw[j * 66 + lane] =
                (unsigned short)((__float_as_uint(u) + 0x8000u) >> 16);
        }
        // p_h = exp2(s'_h)  (log2e folded into g and d)
        const float p0 = EXP2(s0), p1 = EXP2(s1), p2 = EXP2(s2), p3 = EXP2(s3);
        l0 += p0; l1 += p1; l2 += p2; l3 += p3;
        p4s[w][lane] = make_float4(p0, p1, p2, p3);
        WG_FENCE();

        // packed read: 2 bf16 points per ds_read_b32; banks (lane+p2)%32 -> 2-way, free
        const unsigned int* urow = (const unsigned int*)(uw + lane * 66);
        #pragma unroll 16
        for (int p2 = 0; p2 < 32; ++p2) {
            const unsigned int bits = urow[p2];
            const float ulo = __uint_as_float(bits << 16);
            const float uhi = __uint_as_float(bits & 0xFFFF0000u);
            const float4 pa = p4s[w][2 * p2];
            const float4 pb = p4s[w][2 * p2 + 1];
            t0 = fmaf(pa.x, ulo, t0); t0 = fmaf(pb.x, uhi, t0);
            t1 = fmaf(pa.y, ulo, t1); t1 = fmaf(pb.y, uhi, t1);
            t2 = fmaf(pa.z, ulo, t2); t2 = fmaf(pb.z, uhi, t2);
            t3 = fmaf(pa.w, ulo, t3); t3 = fmaf(pb.w, uhi, t3);
        }
        WG_FENCE();   // WAR: before next iteration overwrites uw/p4s
    }

    // wave-reduce l (lane-local partials)
    for (int m = 1; m < 64; m <<= 1) {
        l0 += __shfl_xor(l0, m);
        l1 += __shfl_xor(l1, m);
        l2 += __shfl_xor(l2, m);
        l3 += __shfl_xor(l3, m);
    }

    float* acc = accb + (blockIdx.x & (NSLOT - 1)) * SLOTSTRIDE;
    if (lane == 0) {
        atomicAdd(acc + 0, l0);
        atomicAdd(acc + 1, l1);
        atomicAdd(acc + 2, l2);
        atomicAdd(acc + 3, l3);
    }
    atomicAdd(acc + 4 + 0 * 64 + lane, t0);
    atomicAdd(acc + 4 + 1 * 64 + lane, t1);
    atomicAdd(acc + 4 + 2 * 64 + lane, t2);
    atomicAdd(acc + 4 + 3 * 64 + lane, t3);
}

// ---------------------------------------------------------------------------
__global__ void finish_kernel(const float* __restrict__ W2, const float* __restrict__ b2,
                              const float* __restrict__ ipw, const float* __restrict__ ipb,
                              const float* __restrict__ opw, const float* __restrict__ opb,
                              const float* __restrict__ ws, float* __restrict__ out)
{
    __shared__ float red[260];   // [0..3]=l, [4+h*64+k]=T
    __shared__ float sb[256];    // S-bar per (h, j)
    __shared__ float pl[64];     // pooled
    const int t = threadIdx.x;

    {
        float a = 0.0f;
        for (int s = 0; s < NSLOT; ++s) a += ws[WS_ACC + s * SLOTSTRIDE + t];
        red[t] = a;
        if (t < 4) {
            float a2 = 0.0f;
            for (int s = 0; s < NSLOT; ++s) a2 += ws[WS_ACC + s * SLOTSTRIDE + 256 + t];
            red[256 + t] = a2;
        }
    }
    __syncthreads();

    // S-bar_h[j] = W2[j][:] . (T_h / l_h) + b2[j]
    {
        const int h = t >> 6, j = t & 63;
        const float inv = 1.0f / red[h];
        float a = 0.0f;
        for (int k = 0; k < 64; ++k) a += W2[j * 64 + k] * red[4 + h * 64 + k];
        sb[t] = fmaf(inv, a, b2[j]);
    }
    __syncthreads();

    // pooled[t] = Wv[t][:] . S-bar_h + bv[t]   (Wv = in_proj_w rows 128..191)
    if (t < 64) {
        const int h = t >> 4;
        float a = ipb[128 + t];
        for (int d = 0; d < 64; ++d) a += ipw[(128 + t) * 64 + d] * sb[h * 64 + d];
        pl[t] = a;
    }
    __syncthreads();

    if (t < 64) {
        float a = opb[t];
        for (int p = 0; p < 64; ++p) a += opw[t * 64 + p] * pl[p];
        out[t] = a;
    }
}

// ---------------------------------------------------------------------------
extern "C" void kernel_launch(void* const* d_in, const int* in_sizes, int n_in,
                              void* d_out, int out_size, void* d_ws, size_t ws_size,
                              hipStream_t stream)
{
    const float* rr  = (const float*)d_in[0];   // rho_real  (1024*1024)
    const float* ri  = (const float*)d_in[1];   // rho_imag  (1024*1024)
    // d_in[2..5]: l_A, l_B, Z_A, Z_B — unused by the reference
    const float* W1  = (const float*)d_in[6];   // (64,2)
    const float* b1  = (const float*)d_in[7];   // (64,)
    const float* W2  = (const float*)d_in[8];   // (64,64)
    const float* b2  = (const float*)d_in[9];   // (64,)
    const float* qy  = (const float*)d_in[10];  // (1,64)
    const float* ipw = (const float*)d_in[11];  // (192,64)
    const float* ipb = (const float*)d_in[12];  // (192,)
    const float* opw = (const float*)d_in[13];  // (64,64)
    const float* opb = (const float*)d_in[14];  // (64,)
    float* ws  = (float*)d_ws;
    float* out = (float*)d_out;

    // zero the atomic accumulator region (graph-capturable)
    hipMemsetAsync(ws + WS_ACC, 0, (size_t)NSLOT * SLOTSTRIDE * sizeof(float), stream);
    setup_kernel<<<1, 256, 0, stream>>>(W1, b1, W2, b2, qy, ipw, ipb, ws);
    main_kernel<<<K1_BLOCKS, K1_THREADS, 0, stream>>>(
        rr, ri,
        (const float4*)(ws + WS_C4), (const float4*)(ws + WS_G4),
        ws + WS_D, ws + WS_ACC);
    finish_kernel<<<1, 256, 0, stream>>>(W2, b2, ipw, ipb, opw, opb, ws, out);
}